// Round 2
// baseline (277.090 us; speedup 1.0000x reference)
//
#include <hip/hip_runtime.h>

#define BB 2048
#define AA 96
#define NIN 128
#define NHID 64

__global__ __launch_bounds__(256) void atomwise_kernel(
    const float* __restrict__ rep,
    const int*   __restrict__ zs,
    const float* __restrict__ mask,
    const float* __restrict__ w1,    // [NIN][NHID] row-major
    const float* __restrict__ b1,    // [NHID]
    const float* __restrict__ w2,    // [NHID] (N_OUT=1)
    const float* __restrict__ b2,    // [1]
    const float* __restrict__ aref,  // [MAX_Z] (N_OUT=1)
    const float* __restrict__ mean,  // [1]
    const float* __restrict__ stddev,// [1]
    float* __restrict__ out)         // [BB]
{
    const int atom = blockIdx.x * 256 + threadIdx.x;   // grid sized exactly
    const float* row = rep + (size_t)atom * NIN;

    // acc[j] = b1[j] + sum_k rep[k] * W1[k][j]
    float acc[NHID];
    #pragma unroll
    for (int j = 0; j < NHID; ++j) acc[j] = b1[j];

    #pragma unroll 1
    for (int k = 0; k < NIN; k += 4) {
        const float4 rv = *reinterpret_cast<const float4*>(row + k);
        const float* wr = w1 + k * NHID;   // wave-uniform address -> s_load
        #pragma unroll
        for (int j = 0; j < NHID; ++j) {
            float a = acc[j];
            a = fmaf(rv.x, wr[j            ], a);
            a = fmaf(rv.y, wr[j +     NHID ], a);
            a = fmaf(rv.z, wr[j + 2 * NHID ], a);
            a = fmaf(rv.w, wr[j + 3 * NHID ], a);
            acc[j] = a;
        }
    }

    const float LOG2E = 1.4426950408889634f;
    const float LN2   = 0.6931471805599453f;

    float yi = 0.0f;
    #pragma unroll
    for (int j = 0; j < NHID; ++j) {
        float x  = acc[j];
        float ax = fabsf(x);
        float em = exp2f(-ax * LOG2E);                       // e^{-|x|}
        float sp = fmaxf(x, 0.0f) + log2f(1.0f + em) * LN2;  // softplus(x)
        yi = fmaf(sp - LN2, w2[j], yi);                      // ssp = sp - log(2)
    }

    // (yi + b2) * stddev + mean + atomref[z]
    yi = fmaf(yi + b2[0], stddev[0], mean[0]);
    yi += aref[zs[atom]];

    const int b = atom / AA;
    atomicAdd(out + b, mask[atom] * yi);
}

extern "C" void kernel_launch(void* const* d_in, const int* in_sizes, int n_in,
                              void* d_out, int out_size, void* d_ws, size_t ws_size,
                              hipStream_t stream) {
    const float* rep    = (const float*)d_in[0];
    const int*   zs     = (const int*)  d_in[1];
    const float* mask   = (const float*)d_in[2];
    const float* w1     = (const float*)d_in[3];
    const float* b1     = (const float*)d_in[4];
    const float* w2     = (const float*)d_in[5];
    const float* b2     = (const float*)d_in[6];
    const float* aref   = (const float*)d_in[7];
    const float* mean   = (const float*)d_in[8];
    const float* stddev = (const float*)d_in[9];
    float* out = (float*)d_out;

    // harness re-poisons d_out to 0xAA before every launch; we accumulate with atomics
    (void)hipMemsetAsync(out, 0, (size_t)out_size * sizeof(float), stream);

    const int atoms = BB * AA;               // 196608 = 768 * 256 exactly
    atomwise_kernel<<<dim3(atoms / 256), dim3(256), 0, stream>>>(
        rep, zs, mask, w1, b1, w2, b2, aref, mean, stddev, out);
}